// Round 3
// baseline (1419.903 us; speedup 1.0000x reference)
//
#include <hip/hip_runtime.h>

#define NROW 16384
#define ROWI 10246
#define NSPLIT 16
#define SPLITC 640               // cols per split
#define NCHUNK 40                // chunks of 16 cols per split
#define NSLICE 18                // G:0, D:1..4, A:5..17
#define POUT_F (NSLICE*33*16384)
#define WT_F   (ROWI*32)
#define PTAB_ROWS 3438
#define PTAB_F (PTAB_ROWS*64)

// ---------------- prep kernels ----------------
__global__ void prep_wt(const float* __restrict__ Wg, const float* __restrict__ Wd,
                        const float* __restrict__ Wa, float* __restrict__ Wt) {
  int e = blockIdx.x*256 + threadIdx.x;
  if (e >= WT_F) return;
  int c = e >> 5, d = e & 31;
  float v = 0.f;
  if (c >= 1 && c < 26)         v = Wg[d*25   + (c-1)];
  else if (c >= 26 && c < 2212) v = Wd[d*2186 + (c-26)];
  else if (c >= 2212 && c < 10242) v = Wa[d*8030 + (c-2212)];
  Wt[e] = v;
}

__global__ void prep_p(const float* __restrict__ er, const float* __restrict__ eg,
                       const float* __restrict__ ea, const float* __restrict__ eo,
                       const float* __restrict__ ez, const float* __restrict__ W1,
                       float* __restrict__ P) {
  int id = blockIdx.x*256 + threadIdx.x;
  if (id >= PTAB_F) return;
  int r = id >> 6, o = id & 63;
  const float* emb; int woff;
  if (r < 6)       { emb = er + r*32;       woff = 0;   }
  else if (r < 8)  { emb = eg + (r-6)*32;   woff = 128; }
  else if (r < 15) { emb = ea + (r-8)*32;   woff = 160; }
  else if (r < 36) { emb = eo + (r-15)*32;  woff = 192; }
  else             { emb = ez + (r-36)*32;  woff = 224; }
  const float* w = W1 + o*256 + woff;
  float s = 0.f;
  #pragma unroll
  for (int c2 = 0; c2 < 32; ++c2) s += emb[c2]*w[c2];
  P[id] = s;
}

__global__ void prep_w2t(const float* __restrict__ W2, float* __restrict__ W2t) {
  int id = blockIdx.x*256 + threadIdx.x;
  if (id >= 64*64) return;
  int o = id >> 6, o2 = id & 63;
  W2t[o*64 + o2] = W2[o2*64 + o];
}

// ---------------- main accumulation kernel ----------------
__device__ __forceinline__ void gl_lds4(const int* gsrc, int* ldst) {
  __builtin_amdgcn_global_load_lds(
      (const __attribute__((address_space(1))) unsigned int*)gsrc,
      (__attribute__((address_space(3))) unsigned int*)ldst,
      4, 0, 0);
}

__global__ __launch_bounds__(256, 4) void k1(
    const int* __restrict__ x, const float* __restrict__ Wt, float* __restrict__ pout) {
  const int tid  = threadIdx.x;
  const int wave = tid >> 6, lane = tid & 63;
  const int split = blockIdx.y;
  const int row0w = blockIdx.x*256 + wave*64;   // wave's first row
  const int row   = row0w + lane;
  __shared__ __align__(16) int lds[2][4][1024]; // [buf][wave][64 rows x 16 cols] = 32KB

  // Stage slot s = i*64 + lane holds x[row0w + 4i + q][c0 + colswz(lane)]
  // with q = lane>>4, t = lane&15, colswz = (((t>>2)^q)<<2) | (t&3).
  // Read: row=lane, col-group g -> lds[lane*16 + ((g^(lane&3))<<2)]  (XOR involution)
  const int q = lane >> 4;
  const int t = lane & 15;
  const int colswz = ((((t >> 2) ^ q) & 3) << 2) | (t & 3);
  const int* p0 = x + (size_t)(row0w + q) * ROWI + colswz;

#define STAGE(BUF, C0) do {                                                    \
    const int* _s = p0 + (C0);                                                 \
    _Pragma("unroll")                                                          \
    for (int i = 0; i < 16; ++i)                                               \
      gl_lds4(_s + i*(4*ROWI), &lds[BUF][wave][i*64]);                         \
  } while (0)

#define LDSREAD(BUF, G) (*(const int4*)&lds[BUF][wave][lane*16 + (((G) ^ (lane & 3)) << 2)])

#define FASTCHUNK(ACC, CNT) do {                                               \
    _Pragma("unroll")                                                          \
    for (int g = 0; g < 4; ++g) {                                              \
      const int4 xi = LDSREAD(buf, g);                                         \
      const float xf0=(float)xi.x, xf1=(float)xi.y, xf2=(float)xi.z, xf3=(float)xi.w; \
      const float* wb = Wt + (size_t)(c0 + g*4)*32;                            \
      CNT += (xf0 + xf1) + (xf2 + xf3);                                        \
      _Pragma("unroll")                                                        \
      for (int d = 0; d < 32; ++d) {                                           \
        float a = ACC[d];                                                      \
        a = fmaf(xf0, wb[d],     a);                                           \
        a = fmaf(xf1, wb[32+d],  a);                                           \
        a = fmaf(xf2, wb[64+d],  a);                                           \
        a = fmaf(xf3, wb[96+d],  a);                                           \
        ACC[d] = a;                                                            \
      }                                                                        \
    } } while (0)

  float accG[32], accD[32], accA[32];
  float cntG = 0.f, cntD = 0.f, cntA = 0.f;
  #pragma unroll
  for (int d = 0; d < 32; ++d) { accG[d]=0.f; accD[d]=0.f; accA[d]=0.f; }

  const int cbeg = split * SPLITC;

  STAGE(0, cbeg);
  asm volatile("s_waitcnt vmcnt(0)" ::: "memory");
  STAGE(1, cbeg + 16);

  for (int ck = 0; ck < NCHUNK; ++ck) {
    const int c0  = cbeg + ck*16;
    const int buf = ck & 1;

    if (c0 == 0 || c0 == 16 || c0 == 2208) {
      // boundary chunks: per-column segment select (wave-uniform branches)
      #pragma unroll
      for (int g = 0; g < 4; ++g) {
        const int4 xi = LDSREAD(buf, g);
        const float xfs[4] = {(float)xi.x,(float)xi.y,(float)xi.z,(float)xi.w};
        #pragma unroll
        for (int t2 = 0; t2 < 4; ++t2) {
          const int c = c0 + g*4 + t2;
          if (c == 0) continue;            // col 0 = rate index, excluded
          const float xf = xfs[t2];
          const float* w = Wt + (size_t)c*32;
          if (c < 26) { cntG += xf;
            #pragma unroll
            for (int d = 0; d < 32; ++d) accG[d] = fmaf(xf, w[d], accG[d]);
          } else if (c < 2212) { cntD += xf;
            #pragma unroll
            for (int d = 0; d < 32; ++d) accD[d] = fmaf(xf, w[d], accD[d]);
          } else { cntA += xf;
            #pragma unroll
            for (int d = 0; d < 32; ++d) accA[d] = fmaf(xf, w[d], accA[d]);
          }
        }
      }
    } else if (c0 < 2212) {
      FASTCHUNK(accD, cntD);
    } else {
      FASTCHUNK(accA, cntA);
    }

    // stage ck+1 (issued one full compute-phase ago) must now be complete
    asm volatile("s_waitcnt vmcnt(0)" ::: "memory");
    if (ck + 2 < NCHUNK) STAGE(buf, c0 + 32);   // reuse freed buffer
  }

  if (split == NSPLIT-1) {  // tail columns 10240, 10241 (actor)
    const int* xr = x + (size_t)row*ROWI;
    const float x0 = (float)xr[10240], x1 = (float)xr[10241];
    cntA += x0 + x1;
    #pragma unroll
    for (int d = 0; d < 32; ++d)
      accA[d] = fmaf(x1, Wt[10241*32+d], fmaf(x0, Wt[10240*32+d], accA[d]));
  }

#define STORESL(SL, ACC, CNT) do {                                             \
    float* _p = pout + (size_t)(SL)*33*16384;                                  \
    _Pragma("unroll")                                                          \
    for (int d = 0; d < 32; ++d) _p[(size_t)d*16384 + row] = ACC[d];           \
    _p[(size_t)32*16384 + row] = CNT; } while (0)

  // split0: G->0, D->1 | split1,2: D->1+split | split3: D->4, A->5 | split>=4: A->2+split
  if (split == 0)      { STORESL(0, accG, cntG); STORESL(1, accD, cntD); }
  else if (split < 3)  { STORESL(1 + split, accD, cntD); }
  else if (split == 3) { STORESL(4, accD, cntD); STORESL(5, accA, cntA); }
  else                 { STORESL(2 + split, accA, cntA); }
#undef STAGE
#undef LDSREAD
#undef FASTCHUNK
#undef STORESL
}

// ---------------- reduce + MLP kernel ----------------
__global__ __launch_bounds__(512) void k2(
    const int* __restrict__ x, const float* __restrict__ pout,
    const float* __restrict__ P, const float* __restrict__ W1,
    const float* __restrict__ b1, const float* __restrict__ W2t,
    const float* __restrict__ b2, const float* __restrict__ Wout,
    const float* __restrict__ bout, float* __restrict__ out) {
  const int row = blockIdx.x*512 + threadIdx.x;
  const int* xr = x + (size_t)row*ROWI;
  const int ridx = xr[0];
  const int gi = xr[10242], ai = xr[10243], oi = xr[10244], ari = xr[10245];
  const float* Pr = P + (size_t)ridx*64;
  const float* Pg = P + (size_t)(6 + gi)*64;
  const float* Pa = P + (size_t)(8 + ai)*64;
  const float* Po = P + (size_t)(15 + oi)*64;
  const float* Pz = P + (size_t)(36 + ari)*64;

  float h1[64];
  #pragma unroll
  for (int o = 0; o < 64; ++o)
    h1[o] = b1[o] + ((Pr[o] + Pg[o]) + (Pa[o] + Po[o])) + Pz[o];

#define BAGK2(NSL, SL0, WOFF) do {                                             \
    float m[32];                                                               \
    _Pragma("unroll")                                                          \
    for (int d = 0; d < 32; ++d) {                                             \
      float s = 0.f;                                                           \
      _Pragma("unroll")                                                        \
      for (int k = 0; k < NSL; ++k)                                            \
        s += pout[(size_t)((SL0)+k)*33*16384 + (size_t)d*16384 + row];         \
      m[d] = s;                                                                \
    }                                                                          \
    float cnt = 0.f;                                                           \
    _Pragma("unroll")                                                          \
    for (int k = 0; k < NSL; ++k)                                              \
      cnt += pout[(size_t)((SL0)+k)*33*16384 + (size_t)32*16384 + row];        \
    _Pragma("unroll")                                                          \
    for (int d = 0; d < 32; ++d) m[d] /= cnt;                                  \
    _Pragma("unroll")                                                          \
    for (int c4 = 0; c4 < 8; ++c4) {                                           \
      _Pragma("unroll")                                                        \
      for (int o = 0; o < 64; ++o) {                                           \
        const float* wr = W1 + o*256 + (WOFF) + c4*4;                          \
        float a = h1[o];                                                       \
        a = fmaf(m[c4*4+0], wr[0], a);                                         \
        a = fmaf(m[c4*4+1], wr[1], a);                                         \
        a = fmaf(m[c4*4+2], wr[2], a);                                         \
        a = fmaf(m[c4*4+3], wr[3], a);                                         \
        h1[o] = a;                                                             \
      }                                                                        \
    } } while (0)

  BAGK2(1,  0, 32);   // genre    (slice 0)
  BAGK2(4,  1, 64);   // director (slices 1..4)
  BAGK2(13, 5, 96);   // actor    (slices 5..17)
#undef BAGK2

  #pragma unroll
  for (int o = 0; o < 64; ++o) h1[o] = fmaxf(h1[o], 0.f);

  float h2[64];
  #pragma unroll
  for (int o2 = 0; o2 < 64; ++o2) h2[o2] = b2[o2];
  #pragma unroll
  for (int o = 0; o < 64; ++o) {
    const float h = h1[o];
    const float* wr = W2t + o*64;
    #pragma unroll
    for (int o2 = 0; o2 < 64; ++o2) h2[o2] = fmaf(h, wr[o2], h2[o2]);
  }
  float acc = bout[0];
  #pragma unroll
  for (int o2 = 0; o2 < 64; ++o2) acc = fmaf(fmaxf(h2[o2], 0.f), Wout[o2], acc);
  out[row] = acc;
}

// ---------------- launcher ----------------
extern "C" void kernel_launch(void* const* d_in, const int* in_sizes, int n_in,
                              void* d_out, int out_size, void* d_ws, size_t ws_size,
                              hipStream_t stream) {
  (void)in_sizes; (void)n_in; (void)out_size; (void)ws_size;
  const int*   x        = (const int*)  d_in[0];
  const float* emb_rate = (const float*)d_in[1];
  const float* W_genre  = (const float*)d_in[2];
  const float* W_dir    = (const float*)d_in[3];
  const float* W_actor  = (const float*)d_in[4];
  const float* emb_gen  = (const float*)d_in[5];
  const float* emb_age  = (const float*)d_in[6];
  const float* emb_occ  = (const float*)d_in[7];
  const float* emb_area = (const float*)d_in[8];
  const float* W1   = (const float*)d_in[9];
  const float* b1   = (const float*)d_in[10];
  const float* W2   = (const float*)d_in[11];
  const float* b2   = (const float*)d_in[12];
  const float* Wout = (const float*)d_in[13];
  const float* bout = (const float*)d_in[14];
  float* outp = (float*)d_out;

  float* ws   = (float*)d_ws;
  float* pout = ws;
  float* Wt   = ws + POUT_F;
  float* P    = Wt + WT_F;
  float* W2t  = P + PTAB_F;

  prep_wt<<<(WT_F + 255)/256, 256, 0, stream>>>(W_genre, W_dir, W_actor, Wt);
  prep_p<<<(PTAB_F + 255)/256, 256, 0, stream>>>(emb_rate, emb_gen, emb_age, emb_occ,
                                                 emb_area, W1, P);
  prep_w2t<<<16, 256, 0, stream>>>(W2, W2t);

  dim3 g1(64, NSPLIT);
  k1<<<g1, 256, 0, stream>>>(x, Wt, pout);
  k2<<<32, 512, 0, stream>>>(x, pout, P, W1, b1, W2t, b2, Wout, bout, outp);
}

// Round 4
// 467.434 us; speedup vs baseline: 3.0377x; 3.0377x over previous
//
#include <hip/hip_runtime.h>

#define NROW 16384
#define ROWI 10246
#define NSPLIT 12
#define NSLICE 12                // D: slices 0..2, A: slices 3..11
#define POUT_F (NSLICE*33*16384)
#define WT_F   (ROWI*32)
#define PTAB_ROWS 3438
#define PTAB_F (PTAB_ROWS*64)

// split table: col0 (first column), nck (16-col chunks). D:[32,2208)=136ck, A:[2224,10240)=501ck
__device__ __constant__ int SPLIT_COL0[NSPLIT] =
  {32, 768, 1488, 2224, 3120, 4016, 4912, 5808, 6704, 7600, 8480, 9360};
__device__ __constant__ int SPLIT_NCK[NSPLIT] =
  {46, 45, 45, 56, 56, 56, 56, 56, 56, 55, 55, 55};

// ---------------- prep kernels ----------------
__global__ void prep_wt(const float* __restrict__ Wg, const float* __restrict__ Wd,
                        const float* __restrict__ Wa, float* __restrict__ Wt) {
  int e = blockIdx.x*256 + threadIdx.x;
  if (e >= WT_F) return;
  int c = e >> 5, d = e & 31;
  float v = 0.f;
  if (c >= 1 && c < 26)         v = Wg[d*25   + (c-1)];
  else if (c >= 26 && c < 2212) v = Wd[d*2186 + (c-26)];
  else if (c >= 2212 && c < 10242) v = Wa[d*8030 + (c-2212)];
  Wt[e] = v;
}

__global__ void prep_p(const float* __restrict__ er, const float* __restrict__ eg,
                       const float* __restrict__ ea, const float* __restrict__ eo,
                       const float* __restrict__ ez, const float* __restrict__ W1,
                       float* __restrict__ P) {
  int id = blockIdx.x*256 + threadIdx.x;
  if (id >= PTAB_F) return;
  int r = id >> 6, o = id & 63;
  const float* emb; int woff;
  if (r < 6)       { emb = er + r*32;       woff = 0;   }
  else if (r < 8)  { emb = eg + (r-6)*32;   woff = 128; }
  else if (r < 15) { emb = ea + (r-8)*32;   woff = 160; }
  else if (r < 36) { emb = eo + (r-15)*32;  woff = 192; }
  else             { emb = ez + (r-36)*32;  woff = 224; }
  const float* w = W1 + o*256 + woff;
  float s = 0.f;
  #pragma unroll
  for (int c2 = 0; c2 < 32; ++c2) s += emb[c2]*w[c2];
  P[id] = s;
}

__global__ void prep_w2t(const float* __restrict__ W2, float* __restrict__ W2t) {
  int id = blockIdx.x*256 + threadIdx.x;
  if (id >= 64*64) return;
  int o = id >> 6, o2 = id & 63;
  W2t[o*64 + o2] = W2[o2*64 + o];
}

// ---------------- main accumulation kernel ----------------
__device__ __forceinline__ void gl_lds4(const int* gsrc, int* ldst) {
  __builtin_amdgcn_global_load_lds(
      (const __attribute__((address_space(1))) unsigned int*)gsrc,
      (__attribute__((address_space(3))) unsigned int*)ldst,
      4, 0, 0);
}

__global__ __launch_bounds__(256, 2) void k1(
    const int* __restrict__ x, const float* __restrict__ Wt, float* __restrict__ pout) {
  const int tid  = threadIdx.x;
  const int wave = tid >> 6, lane = tid & 63;
  const int split = blockIdx.y;
  const int row0w = blockIdx.x*256 + wave*64;   // wave's first row
  const int row   = row0w + lane;
  __shared__ __align__(16) int lds[3][4][1024]; // [buf][wave][64 rows x 16 cols] = 48KB

  // Stage slot s = i*64 + lane holds x[row0w + 4i + q][col0 + ck*16 + colswz(t,q)]
  // q = lane>>4, t = lane&15, colswz = ((((t>>2)^q)&3)<<2) | (t&3).
  // Read: row=lane, group g -> lds[lane*16 + ((g^(lane&3))<<2)]  (XOR involution; verified r2/r3)
  const int q = lane >> 4;
  const int t = lane & 15;
  const int colswz = ((((t >> 2) ^ q) & 3) << 2) | (t & 3);

  const int col0 = SPLIT_COL0[split];
  const int nck  = SPLIT_NCK[split];
  const int* p0 = x + (size_t)(row0w + q) * ROWI + col0 + colswz;

#define STAGE(BUF, CKOFF) do {                                                 \
    const int* _s = p0 + (CKOFF);                                              \
    int* _l = &lds[BUF][wave][0];                                              \
    _Pragma("unroll")                                                          \
    for (int i = 0; i < 16; ++i)                                               \
      gl_lds4(_s + i*(4*ROWI), _l + i*64);                                     \
  } while (0)

  float acc[32];
  float cnt = 0.f;
  #pragma unroll
  for (int d = 0; d < 32; ++d) acc[d] = 0.f;

  STAGE(0, 0);
  STAGE(1, 16);

  int bcur = 0;
  for (int ck = 0; ck < nck; ++ck) {
    int bst = bcur + 2; if (bst >= 3) bst -= 3;
    if (ck + 2 < nck) {
      STAGE(bst, (ck + 2) * 16);
      asm volatile("s_waitcnt vmcnt(32)" ::: "memory");  // oldest stage (chunk ck) done
    } else if (ck + 1 < nck) {
      asm volatile("s_waitcnt vmcnt(16)" ::: "memory");
    } else {
      asm volatile("s_waitcnt vmcnt(0)" ::: "memory");
    }

    const int c0 = col0 + ck*16;
    const int* lbase = &lds[bcur][wave][lane*16];
    #pragma unroll
    for (int g = 0; g < 4; ++g) {
      const int4 xi = *(const int4*)&lbase[((g ^ (lane & 3)) << 2)];
      const float xf0=(float)xi.x, xf1=(float)xi.y, xf2=(float)xi.z, xf3=(float)xi.w;
      const float* wb = Wt + (size_t)(c0 + g*4)*32;
      cnt += (xf0 + xf1) + (xf2 + xf3);
      #pragma unroll
      for (int d = 0; d < 32; ++d) {
        float a = acc[d];
        a = fmaf(xf0, wb[d],     a);
        a = fmaf(xf1, wb[32+d],  a);
        a = fmaf(xf2, wb[64+d],  a);
        a = fmaf(xf3, wb[96+d],  a);
        acc[d] = a;
      }
    }
    bcur = (bcur == 2) ? 0 : bcur + 1;
  }

  // store slice = split (d-major for coalesced k2 reads)
  float* _p = pout + (size_t)split*33*16384;
  #pragma unroll
  for (int d = 0; d < 32; ++d) _p[(size_t)d*16384 + row] = acc[d];
  _p[(size_t)32*16384 + row] = cnt;
#undef STAGE
}

// ---------------- boundary + reduce + MLP kernel ----------------
__global__ __launch_bounds__(64, 1) void k2(
    const int* __restrict__ x, const float* __restrict__ pout,
    const float* __restrict__ Wt, const float* __restrict__ P,
    const float* __restrict__ W1, const float* __restrict__ b1,
    const float* __restrict__ W2t, const float* __restrict__ b2,
    const float* __restrict__ Wout, const float* __restrict__ bout,
    float* __restrict__ out) {
  const int row = blockIdx.x*64 + threadIdx.x;
  const int* xr = x + (size_t)row*ROWI;

#define PSL(SL, D) pout[(size_t)((SL)*33 + (D))*16384 + row]

  float mG[32], mD[32], mA[32];
  float cG = 0.f, cD = 0.f, cA = 0.f;
  #pragma unroll
  for (int d = 0; d < 32; ++d) {
    mG[d] = 0.f;
    mD[d] = PSL(0, d) + PSL(1, d) + PSL(2, d);
    float s = 0.f;
    #pragma unroll
    for (int k = 3; k < 12; ++k) s += PSL(k, d);
    mA[d] = s;
  }
  cD = PSL(0, 32) + PSL(1, 32) + PSL(2, 32);
  #pragma unroll
  for (int k = 3; k < 12; ++k) cA += PSL(k, 32);

  // boundary region 1: columns [0,32)  (col 0 = rate index, excluded)
  {
    int xb[32];
    #pragma unroll
    for (int i = 0; i < 16; ++i) {
      int2 v = *(const int2*)&xr[2*i];
      xb[2*i] = v.x; xb[2*i+1] = v.y;
    }
    #pragma unroll
    for (int c = 1; c < 32; ++c) {
      const float xf = (float)xb[c];
      const float* w = Wt + c*32;
      if (c < 26) { cG += xf;
        #pragma unroll
        for (int d = 0; d < 32; ++d) mG[d] = fmaf(xf, w[d], mG[d]);
      } else { cD += xf;
        #pragma unroll
        for (int d = 0; d < 32; ++d) mD[d] = fmaf(xf, w[d], mD[d]);
      }
    }
  }
  // boundary region 2: columns [2208,2224)
  {
    int xb[16];
    #pragma unroll
    for (int i = 0; i < 8; ++i) {
      int2 v = *(const int2*)&xr[2208 + 2*i];
      xb[2*i] = v.x; xb[2*i+1] = v.y;
    }
    #pragma unroll
    for (int c2 = 0; c2 < 16; ++c2) {
      const int c = 2208 + c2;
      const float xf = (float)xb[c2];
      const float* w = Wt + c*32;
      if (c < 2212) { cD += xf;
        #pragma unroll
        for (int d = 0; d < 32; ++d) mD[d] = fmaf(xf, w[d], mD[d]);
      } else { cA += xf;
        #pragma unroll
        for (int d = 0; d < 32; ++d) mA[d] = fmaf(xf, w[d], mA[d]);
      }
    }
  }
  // tail columns 10240, 10241 (actor)
  {
    const float t0 = (float)xr[10240], t1 = (float)xr[10241];
    cA += t0 + t1;
    #pragma unroll
    for (int d = 0; d < 32; ++d)
      mA[d] = fmaf(t1, Wt[10241*32+d], fmaf(t0, Wt[10240*32+d], mA[d]));
  }

  #pragma unroll
  for (int d = 0; d < 32; ++d) { mG[d] /= cG; mD[d] /= cD; mA[d] /= cA; }

  // index-embedding contributions via folded P table
  const int ridx = xr[0];
  const int gi = xr[10242], ai = xr[10243], oi = xr[10244], ari = xr[10245];
  const float* Pr = P + (size_t)ridx*64;
  const float* Pg = P + (size_t)(6 + gi)*64;
  const float* Pa = P + (size_t)(8 + ai)*64;
  const float* Po = P + (size_t)(15 + oi)*64;
  const float* Pz = P + (size_t)(36 + ari)*64;

  float h1[64];
  #pragma unroll
  for (int o = 0; o < 64; ++o)
    h1[o] = b1[o] + ((Pr[o] + Pg[o]) + (Pa[o] + Po[o])) + Pz[o];

  // fold means through W1 (rows uniform -> scalar loads), fused ReLU
  #pragma unroll
  for (int o = 0; o < 64; ++o) {
    const float* w = W1 + o*256;
    float a = h1[o];
    #pragma unroll
    for (int d = 0; d < 32; ++d) a = fmaf(mG[d], w[32+d], a);
    #pragma unroll
    for (int d = 0; d < 32; ++d) a = fmaf(mD[d], w[64+d], a);
    #pragma unroll
    for (int d = 0; d < 32; ++d) a = fmaf(mA[d], w[96+d], a);
    h1[o] = fmaxf(a, 0.f);
  }

  float h2[64];
  #pragma unroll
  for (int o2 = 0; o2 < 64; ++o2) h2[o2] = b2[o2];
  #pragma unroll
  for (int o = 0; o < 64; ++o) {
    const float h = h1[o];
    const float* wr = W2t + o*64;
    #pragma unroll
    for (int o2 = 0; o2 < 64; ++o2) h2[o2] = fmaf(h, wr[o2], h2[o2]);
  }
  float acc = bout[0];
  #pragma unroll
  for (int o2 = 0; o2 < 64; ++o2) acc = fmaf(fmaxf(h2[o2], 0.f), Wout[o2], acc);
  out[row] = acc;
#undef PSL
}

// ---------------- launcher ----------------
extern "C" void kernel_launch(void* const* d_in, const int* in_sizes, int n_in,
                              void* d_out, int out_size, void* d_ws, size_t ws_size,
                              hipStream_t stream) {
  (void)in_sizes; (void)n_in; (void)out_size; (void)ws_size;
  const int*   x        = (const int*)  d_in[0];
  const float* emb_rate = (const float*)d_in[1];
  const float* W_genre  = (const float*)d_in[2];
  const float* W_dir    = (const float*)d_in[3];
  const float* W_actor  = (const float*)d_in[4];
  const float* emb_gen  = (const float*)d_in[5];
  const float* emb_age  = (const float*)d_in[6];
  const float* emb_occ  = (const float*)d_in[7];
  const float* emb_area = (const float*)d_in[8];
  const float* W1   = (const float*)d_in[9];
  const float* b1   = (const float*)d_in[10];
  const float* W2   = (const float*)d_in[11];
  const float* b2   = (const float*)d_in[12];
  const float* Wout = (const float*)d_in[13];
  const float* bout = (const float*)d_in[14];
  float* outp = (float*)d_out;

  float* ws   = (float*)d_ws;
  float* pout = ws;
  float* Wt   = ws + POUT_F;
  float* P    = Wt + WT_F;
  float* W2t  = P + PTAB_F;

  prep_wt<<<(WT_F + 255)/256, 256, 0, stream>>>(W_genre, W_dir, W_actor, Wt);
  prep_p<<<(PTAB_F + 255)/256, 256, 0, stream>>>(emb_rate, emb_gen, emb_age, emb_occ,
                                                 emb_area, W1, P);
  prep_w2t<<<16, 256, 0, stream>>>(W2, W2t);

  dim3 g1(64, NSPLIT);
  k1<<<g1, 256, 0, stream>>>(x, Wt, pout);
  k2<<<256, 64, 0, stream>>>(x, pout, Wt, P, W1, b1, W2t, b2, Wout, bout, outp);
}